// Round 15
// baseline (1359.615 us; speedup 1.0000x reference)
//
#include <hip/hip_runtime.h>
#include <hip/hip_bf16.h>
#include <cstdint>
#include <cstddef>

typedef __attribute__((ext_vector_type(4))) float floatx4;
typedef __attribute__((ext_vector_type(8))) short shortx8;
typedef __attribute__((ext_vector_type(2))) __fp16 f16x2;

#define T_SEQ 512
#define NIN   512
#define BATCH 256
#define HID   256
#define G3    768
#define NC    101

static __device__ __forceinline__ unsigned short f2bf(float f){
  unsigned int u = __float_as_uint(f);
  u += 0x7FFFu + ((u >> 16) & 1u);
  return (unsigned short)(u >> 16);
}

static __device__ __forceinline__ float dot2acc(f16x2 w, f16x2 h, float acc){
#if __has_builtin(__builtin_amdgcn_fdot2)
  return __builtin_amdgcn_fdot2(w, h, acc, false);
#else
  return acc + (float)w[0]*(float)h[0] + (float)w[1]*(float)h[1];
#endif
}

// quad-lane butterfly add via DPP (VALU pipe, no LDS). 0xB1 = xor1, 0x4E = xor2.
template<int CTRL>
static __device__ __forceinline__ float dppadd(float v){
  return v + __int_as_float(__builtin_amdgcn_update_dpp(
      0, __float_as_int(v), CTRL, 0xF, 0xF, true));
}

// ---------------- Pre-pass: f32 -> bf16 (vectorized). One-time conversion so
// gemm staging does pure 16B copies instead of per-element f2bf VALU work.
__global__ __launch_bounds__(256) void cvt_bf16(
    const float* __restrict__ src, unsigned short* __restrict__ dst, int n4)
{
  int i = blockIdx.x * 256 + threadIdx.x;
  const int stride = gridDim.x * 256;
  for (; i < n4; i += stride){
    const float4 v = *(const float4*)(src + (size_t)i * 4);
    union { unsigned short u[4]; uint2 q; } p;
    p.u[0] = f2bf(v.x); p.u[1] = f2bf(v.y); p.u[2] = f2bf(v.z); p.u[3] = f2bf(v.w);
    *(uint2*)(dst + (size_t)i * 4) = p.q;
  }
}

// ---------------- Phase A: xg[b*Tc+tt][n] = x[b,t0+tt,:].Wih[n,:] + bih[n]
// (unchanged from R12 — measured working)
#define BM 128
#define BN 128
#define BK 64
#define LDK 72

__global__ __launch_bounds__(256) void gemm_xg(
    const unsigned short* __restrict__ xbf, const unsigned short* __restrict__ wbf,
    const float* __restrict__ bih, float* __restrict__ xg,
    int t0, int tcLog2)
{
  __shared__ unsigned short As[BM*LDK];
  __shared__ unsigned short Bs[BN*LDK];
  const int tid  = threadIdx.x;
  const int bn   = blockIdx.x;   // N fastest: 6 consecutive blocks share one x-tile (L2 reuse)
  const int bm   = blockIdx.y;
  const int w    = tid >> 6;
  const int l    = tid & 63;
  const int lm   = l & 15;
  const int quad = l >> 4;

  const int srow2 = tid >> 3;        // 0..31
  const int scol8 = (tid & 7) * 8;   // 0,8,..,56
  const int tcMask = (1 << tcLog2) - 1;

  floatx4 acc[2][8];
  #pragma unroll
  for (int mt = 0; mt < 2; ++mt)
    #pragma unroll
    for (int nt = 0; nt < 8; ++nt)
      acc[mt][nt] = (floatx4){0.f, 0.f, 0.f, 0.f};

  for (int kt = 0; kt < NIN / BK; ++kt){
    const int k0 = kt * BK;
    __syncthreads();
    #pragma unroll
    for (int p = 0; p < 4; ++p){
      const int r  = p * 32 + srow2;
      const int gm = bm * BM + r;
      const int b  = gm >> tcLog2;
      const int tt = gm & tcMask;
      *(uint4*)&As[r * LDK + scol8] =
          *(const uint4*)(xbf + (size_t)(b * T_SEQ + t0 + tt) * NIN + k0 + scol8);
      const int gn = bn * BN + r;
      *(uint4*)&Bs[r * LDK + scol8] =
          *(const uint4*)(wbf + (size_t)gn * NIN + k0 + scol8);
    }
    __syncthreads();
    #pragma unroll
    for (int ks = 0; ks < 2; ++ks){
      const int kk = ks * 32 + quad * 8;
      shortx8 af[2], bfr[8];
      #pragma unroll
      for (int mt = 0; mt < 2; ++mt)
        af[mt] = *(const shortx8*)&As[(w * 32 + mt * 16 + lm) * LDK + kk];
      #pragma unroll
      for (int nt = 0; nt < 8; ++nt)
        bfr[nt] = *(const shortx8*)&Bs[(nt * 16 + lm) * LDK + kk];
      #pragma unroll
      for (int mt = 0; mt < 2; ++mt)
        #pragma unroll
        for (int nt = 0; nt < 8; ++nt)
          acc[mt][nt] = __builtin_amdgcn_mfma_f32_16x16x32_bf16(af[mt], bfr[nt], acc[mt][nt], 0, 0, 0);
    }
  }

  #pragma unroll
  for (int mt = 0; mt < 2; ++mt){
    #pragma unroll
    for (int nt = 0; nt < 8; ++nt){
      #pragma unroll
      for (int i = 0; i < 4; ++i){
        const int ml = w * 32 + mt * 16 + quad * 4 + i;
        const int nl = nt * 16 + lm;
        const int gm = bm * BM + ml;
        const int gn = bn * BN + nl;
        xg[(size_t)gm * G3 + gn] = acc[mt][nt][i] + bih[gn];
      }
    }
  }
}

// ---------------- Phase B: sequential GRU, quarter-K split. 1024 threads,
// thread (j = tid>>2, q = tid&3) owns j's gates over h[64q..64q+64).
// Weights: 3 gates x 32 f16x2 = 96 VGPRs -> total demand ~130 vs the 128
// arch cap at 4 waves/SIMD (amdgpu_waves_per_eu(4,4) pins it; R9 showed the
// compiler defects to 64 without the pin). This kills the accum-file shuttle
// tax that inflated R0/R1's VALU by ~2.3x (585 vs 250 insts/wave/step).
// Quarter reduce via DPP quad_perm; h mirror layout identical to R1's
// proven 144B-stride disjoint-bank-group pattern.
#define HSTRIDE 280   // u16 per buffer: pos(k) = k + 8*(k>>6); 280*2 = 560 B (16B-aligned)

__global__ __attribute__((amdgpu_flat_work_group_size(1024, 1024), amdgpu_waves_per_eu(4, 4)))
void gru_steps(
    const float* __restrict__ xg, const float* __restrict__ Whh,
    const float* __restrict__ bhh, float* __restrict__ hstate, int Tc)
{
  __shared__ alignas(16) unsigned short hph[2][HSTRIDE];
  const int b   = blockIdx.x;
  const int tid = threadIdx.x;
  const int j   = tid >> 2;        // 0..255
  const int q   = tid & 3;         // K-quarter
  const int jpos = j + ((j >> 6) << 3);   // padded u16 position of j

  // Weights: rows j, j+256, j+512, cols [64q, 64q+64) -> 96 f16x2 regs
  f16x2 wr[32], wz[32], wn[32];
  {
    const float4* r4 = (const float4*)(Whh + (size_t)j * HID + q * 64);
    const float4* z4 = (const float4*)(Whh + (size_t)(j + 256) * HID + q * 64);
    const float4* n4 = (const float4*)(Whh + (size_t)(j + 512) * HID + q * 64);
    #pragma unroll
    for (int k = 0; k < 16; ++k){
      float4 v = r4[k];
      wr[2*k]   = __builtin_amdgcn_cvt_pkrtz(v.x, v.y);
      wr[2*k+1] = __builtin_amdgcn_cvt_pkrtz(v.z, v.w);
    }
    #pragma unroll
    for (int k = 0; k < 16; ++k){
      float4 v = z4[k];
      wz[2*k]   = __builtin_amdgcn_cvt_pkrtz(v.x, v.y);
      wz[2*k+1] = __builtin_amdgcn_cvt_pkrtz(v.z, v.w);
    }
    #pragma unroll
    for (int k = 0; k < 16; ++k){
      float4 v = n4[k];
      wn[2*k]   = __builtin_amdgcn_cvt_pkrtz(v.x, v.y);
      wn[2*k+1] = __builtin_amdgcn_cvt_pkrtz(v.z, v.w);
    }
  }
  const float br = bhh[j];
  const float bz = bhh[j + 256];
  const float bn = bhh[j + 512];

  float hj = hstate[b * HID + j];
  if (q == 0){
    union { __fp16 f; unsigned short u; } cv;
    cv.f = (__fp16)hj;
    hph[0][jpos] = cv.u;
  }
  __syncthreads();

  const float* xgrow = xg + (size_t)b * Tc * G3 + j;
  float xr = xgrow[0], xz = xgrow[256], xn = xgrow[512];

  #pragma unroll 1
  for (int t = 0; t < Tc; ++t){
    const int tn = (t + 1 < Tc) ? (t + 1) : t;
    const float nxr = xgrow[(size_t)tn * G3];
    const float nxz = xgrow[(size_t)tn * G3 + 256];
    const float nxn = xgrow[(size_t)tn * G3 + 512];

    // This lane's 64 h-halves: 8 x b128 at byte 144*q + 16*i.
    // Per b128 inst the wave's 4 distinct addresses land in disjoint 4-bank
    // groups (144B stride), 16-way broadcast within each -> conflict-free.
    const uint4* hp4 = (const uint4*)(&hph[t & 1][0]) + 9 * q;

    float ar = 0.f, az = 0.f, an = 0.f;
    #pragma unroll
    for (int hb = 0; hb < 2; ++hb){
      uint4 hv[4];
      #pragma unroll
      for (int i = 0; i < 4; ++i) hv[i] = hp4[hb * 4 + i];
      #pragma unroll
      for (int i = 0; i < 4; ++i){
        union { unsigned int u; f16x2 h; } c0, c1, c2, c3;
        c0.u = hv[i].x; c1.u = hv[i].y; c2.u = hv[i].z; c3.u = hv[i].w;
        const int p = hb * 16 + 4 * i;
        ar = dot2acc(wr[p    ], c0.h, ar);
        az = dot2acc(wz[p    ], c0.h, az);
        an = dot2acc(wn[p    ], c0.h, an);
        ar = dot2acc(wr[p + 1], c1.h, ar);
        az = dot2acc(wz[p + 1], c1.h, az);
        an = dot2acc(wn[p + 1], c1.h, an);
        ar = dot2acc(wr[p + 2], c2.h, ar);
        az = dot2acc(wz[p + 2], c2.h, az);
        an = dot2acc(wn[p + 2], c2.h, an);
        ar = dot2acc(wr[p + 3], c3.h, ar);
        az = dot2acc(wz[p + 3], c3.h, az);
        an = dot2acc(wn[p + 3], c3.h, an);
      }
    }

    // quad butterfly over the 4 K-quarter lanes (VALU-only, no LDS pipe)
    ar = dppadd<0xB1>(ar); az = dppadd<0xB1>(az); an = dppadd<0xB1>(an);
    ar = dppadd<0x4E>(ar); az = dppadd<0x4E>(az); an = dppadd<0x4E>(an);

    const float hr = ar + br;
    const float hz = az + bz;
    const float hn = an + bn;

    const float r = 1.f / (1.f + __expf(-(xr + hr)));
    const float z = 1.f / (1.f + __expf(-(xz + hz)));
    const float a = xn + r * hn;
    const float ex = __expf(-2.f * fabsf(a));
    float n = (1.f - ex) / (1.f + ex);
    n = copysignf(n, a);
    const float hnew = fmaf(z, hj - n, n);   // (1-z)*n + z*h

    hj = hnew;
    if (q == 0){
      union { __fp16 f; unsigned short u; } cv;
      cv.f = (__fp16)hj;
      hph[1 - (t & 1)][jpos] = cv.u;   // write other buffer: no race with reads
    }
    __syncthreads();                    // single barrier: new buffer visible
    xr = nxr; xz = nxz; xn = nxn;
  }

  if (q == 0) hstate[b * HID + j] = hj;
}

// ---------------- FC
__global__ __launch_bounds__(128) void fc_kernel(
    const float* __restrict__ hstate, const float* __restrict__ fw,
    const float* __restrict__ fb, float* __restrict__ out)
{
  __shared__ float hs[HID];
  const int b = blockIdx.x;
  const int t = threadIdx.x;
  hs[t]       = hstate[b * HID + t];
  hs[t + 128] = hstate[b * HID + t + 128];
  __syncthreads();
  if (t < NC){
    float acc = fb[t];
    const float4* w4 = (const float4*)(fw + (size_t)t * HID);
    const float4* h4 = (const float4*)hs;
    #pragma unroll
    for (int k = 0; k < 64; ++k){
      const float4 wv = w4[k];
      const float4 hv = h4[k];
      acc += wv.x * hv.x + wv.y * hv.y + wv.z * hv.z + wv.w * hv.w;
    }
    out[b * NC + t] = acc;
  }
}

extern "C" void kernel_launch(void* const* d_in, const int* in_sizes, int n_in,
                              void* d_out, int out_size, void* d_ws, size_t ws_size,
                              hipStream_t stream)
{
  const float* x   = (const float*)d_in[0];
  const float* Wih = (const float*)d_in[1];
  const float* Whh = (const float*)d_in[2];
  const float* bih = (const float*)d_in[3];
  const float* bhh = (const float*)d_in[4];
  const float* fcw = (const float*)d_in[5];
  const float* fcb = (const float*)d_in[6];
  float* out = (float*)d_out;

  // workspace layout: hstate | xbf (bf16 x) | wbf (bf16 Wih) | xg (f32)
  const size_t hBytes   = (size_t)BATCH * HID * sizeof(float);          // 256 KB
  const size_t xbfBytes = (size_t)BATCH * T_SEQ * NIN * 2;              // 134 MB
  const size_t wbfBytes = (size_t)G3 * NIN * 2;                         // 0.75 MB
  float* hst = (float*)d_ws;
  unsigned short* xbf = (unsigned short*)((char*)d_ws + hBytes);
  unsigned short* wbf = (unsigned short*)((char*)d_ws + hBytes + xbfBytes);
  float* xg = (float*)((char*)d_ws + hBytes + xbfBytes + wbfBytes);

  const size_t fixed = hBytes + xbfBytes + wbfBytes;
  const size_t perT  = (size_t)BATCH * G3 * sizeof(float);
  const size_t avail = (ws_size > fixed) ? (ws_size - fixed) : 0;
  int tcLog2 = 9;
  while (tcLog2 > 0 && perT * ((size_t)1 << tcLog2) > avail) --tcLog2;
  const int Tc = 1 << tcLog2;

  cvt_bf16<<<2048, 256, 0, stream>>>(x, xbf, BATCH * T_SEQ * NIN / 4);
  cvt_bf16<<<384, 256, 0, stream>>>(Wih, wbf, G3 * NIN / 4);
  (void)hipMemsetAsync(hst, 0, hBytes, stream);
  for (int t0 = 0; t0 < T_SEQ; t0 += Tc){
    dim3 grid(6, 2 * Tc);
    gemm_xg<<<grid, 256, 0, stream>>>(xbf, wbf, bih, xg, t0, tcLog2);
    gru_steps<<<BATCH, 1024, 0, stream>>>(xg, Whh, bhh, hst, Tc);
  }
  fc_kernel<<<BATCH, 128, 0, stream>>>(hst, fcw, fcb, out);
}